// Round 1
// baseline (58.777 us; speedup 1.0000x reference)
//
#include <hip/hip_runtime.h>

// GraphSearchPolicy fused kernel for MI355X (gfx950).
// B=2048, A=256, DE=128, DH=256, DR=128, DIN=512, ACT=256, NR=1000.
// One block = 4 batch rows, 256 threads. Grid = B/4 = 512 blocks.

#define BB   4      // batch rows per block
#define DE   128
#define DH   256
#define DR   128
#define DIN  512    // DE + DH + DR
#define ACT  256    // hidden width (= DE + DR)
#define AA   256    // action-space width

__global__ __launch_bounds__(256) void policy_kernel(
    const int*   __restrict__ e,
    const int*   __restrict__ q,
    const float* __restrict__ H,
    const int*   __restrict__ r_space,
    const float* __restrict__ r_mask,
    const float* __restrict__ entity_emb,
    const float* __restrict__ rel_emb,
    const float* __restrict__ W1,
    const float* __restrict__ b1,
    const float* __restrict__ W2,
    const float* __restrict__ b2,
    float* __restrict__ dist_out,
    float* __restrict__ ent_out)
{
    const int t  = threadIdx.x;            // 0..255
    const int b0 = blockIdx.x * BB;

    __shared__ float xinT[DIN][BB];        // transposed input rows   (8 KB)
    __shared__ float hmidT[ACT][BB];       // transposed hidden       (4 KB)
    __shared__ float x2s[BB][DR];          // second-layer output     (2 KB)
    __shared__ float wredM[4][BB];
    __shared__ float wredS[4][BB];
    __shared__ float wredL[4][BB];

    // ---------- stage X = concat(E[e], H, Q[q]) transposed into LDS ----------
    for (int i = t; i < DIN * BB; i += 256) {
        const int c  = i >> 2;             // column 0..511
        const int bb = i & 3;
        const int b  = b0 + bb;
        float v;
        if (c < DE)           v = entity_emb[e[b] * DE + c];
        else if (c < DE + DH) v = H[b * DH + (c - DE)];
        else                  v = rel_emb[q[b] * DR + (c - DE - DH)];
        xinT[c][bb] = v;
    }
    __syncthreads();

    // ---------- layer 1: h = relu(X @ W1 + b1); thread t owns column t -------
    {
        const float bias = b1[t];
        float a0 = bias, a1 = bias, a2 = bias, a3 = bias;
        const float4* xv = (const float4*)&xinT[0][0];   // xv[k] = rows 0..3 at col k
        #pragma unroll 8
        for (int k = 0; k < DIN; ++k) {
            const float  w  = W1[k * ACT + t];           // coalesced, L2-resident
            const float4 x4 = xv[k];                     // LDS broadcast
            a0 = fmaf(x4.x, w, a0);
            a1 = fmaf(x4.y, w, a1);
            a2 = fmaf(x4.z, w, a2);
            a3 = fmaf(x4.w, w, a3);
        }
        float4 hv;
        hv.x = fmaxf(a0, 0.f); hv.y = fmaxf(a1, 0.f);
        hv.z = fmaxf(a2, 0.f); hv.w = fmaxf(a3, 0.f);
        ((float4*)&hmidT[0][0])[t] = hv;                 // contiguous b128 write
    }
    __syncthreads();

    // ---------- layer 2: x2 = h @ W2 + b2 ------------------------------------
    // 256 threads: j = t&127 (output col), g = t>>7 owns rows {2g, 2g+1}
    {
        const int j = t & 127;
        const int g = t >> 7;
        const float bias = b2[j];
        float a0 = bias, a1 = bias;
        const float4* hv4 = (const float4*)&hmidT[0][0];
        #pragma unroll 8
        for (int k = 0; k < ACT; ++k) {
            const float  w  = W2[k * DR + j];
            const float4 hk = hv4[k];                    // LDS broadcast
            const float h0 = g ? hk.z : hk.x;            // static extracts + cndmask
            const float h1 = g ? hk.w : hk.y;
            a0 = fmaf(h0, w, a0);
            a1 = fmaf(h1, w, a1);
        }
        x2s[2 * g + 0][j] = a0;
        x2s[2 * g + 1][j] = a1;
    }
    __syncthreads();

    // ---------- logits: thread t = action t, rows bb = 0..3 ------------------
    float lg[BB];
    #pragma unroll
    for (int bb = 0; bb < BB; ++bb) {
        const int b = b0 + bb;
        const int r = r_space[b * AA + t];
        const float4* rr = (const float4*)(rel_emb + r * DR);   // gathered, L2-hit
        const float4* xx = (const float4*)&x2s[bb][0];          // LDS broadcast
        float s = 0.f;
        #pragma unroll
        for (int d = 0; d < DR / 4; ++d) {
            const float4 rv = rr[d];
            const float4 x4 = xx[d];
            s = fmaf(rv.x, x4.x, s);
            s = fmaf(rv.y, x4.y, s);
            s = fmaf(rv.z, x4.z, s);
            s = fmaf(rv.w, x4.w, s);
        }
        lg[bb] = s - (1.0f - r_mask[b * AA + t]) * 1e31f;
    }

    const int wid = t >> 6;

    // ---------- block-wide max per row ---------------------------------------
    float m[BB];
    #pragma unroll
    for (int bb = 0; bb < BB; ++bb) m[bb] = lg[bb];
    #pragma unroll
    for (int off = 32; off >= 1; off >>= 1) {
        #pragma unroll
        for (int bb = 0; bb < BB; ++bb)
            m[bb] = fmaxf(m[bb], __shfl_xor(m[bb], off, 64));
    }
    if ((t & 63) == 0) {
        #pragma unroll
        for (int bb = 0; bb < BB; ++bb) wredM[wid][bb] = m[bb];
    }
    __syncthreads();
    #pragma unroll
    for (int bb = 0; bb < BB; ++bb)
        m[bb] = fmaxf(fmaxf(wredM[0][bb], wredM[1][bb]),
                      fmaxf(wredM[2][bb], wredM[3][bb]));

    // ---------- exp; joint reduce of S = sum p and SL = sum p*logit ----------
    float p[BB], s[BB], sl[BB];
    #pragma unroll
    for (int bb = 0; bb < BB; ++bb) {
        p[bb]  = __expf(lg[bb] - m[bb]);
        s[bb]  = p[bb];
        sl[bb] = p[bb] * (lg[bb] - m[bb]);   // relative logit avoids overflow
    }
    #pragma unroll
    for (int off = 32; off >= 1; off >>= 1) {
        #pragma unroll
        for (int bb = 0; bb < BB; ++bb) {
            s[bb]  += __shfl_xor(s[bb],  off, 64);
            sl[bb] += __shfl_xor(sl[bb], off, 64);
        }
    }
    if ((t & 63) == 0) {
        #pragma unroll
        for (int bb = 0; bb < BB; ++bb) { wredS[wid][bb] = s[bb]; wredL[wid][bb] = sl[bb]; }
    }
    __syncthreads();
    float S[BB], SL[BB];
    #pragma unroll
    for (int bb = 0; bb < BB; ++bb) {
        S[bb]  = wredS[0][bb] + wredS[1][bb] + wredS[2][bb] + wredS[3][bb];
        SL[bb] = wredL[0][bb] + wredL[1][bb] + wredL[2][bb] + wredL[3][bb];
    }

    // ---------- dist + entropy ------------------------------------------------
    #pragma unroll
    for (int bb = 0; bb < BB; ++bb) {
        const float inv = 1.0f / S[bb];
        dist_out[(b0 + bb) * AA + t] = p[bb] * inv;
    }
    if (t == 0) {
        #pragma unroll
        for (int bb = 0; bb < BB; ++bb) {
            // H = log S - SL/S   (entropy of softmax over (lg - m))
            ent_out[b0 + bb] = __logf(S[bb]) - SL[bb] / S[bb];
        }
    }
}

extern "C" void kernel_launch(void* const* d_in, const int* in_sizes, int n_in,
                              void* d_out, int out_size, void* d_ws, size_t ws_size,
                              hipStream_t stream) {
    const int*   e          = (const int*)  d_in[0];
    const int*   q          = (const int*)  d_in[1];
    const float* H          = (const float*)d_in[2];
    const int*   r_space    = (const int*)  d_in[3];
    const float* r_mask     = (const float*)d_in[4];
    const float* entity_emb = (const float*)d_in[5];
    const float* rel_emb    = (const float*)d_in[6];
    const float* W1         = (const float*)d_in[7];
    const float* b1         = (const float*)d_in[8];
    const float* W2         = (const float*)d_in[9];
    const float* b2         = (const float*)d_in[10];

    const int B = in_sizes[0];              // 2048
    float* dist_out = (float*)d_out;        // [B, 256]
    float* ent_out  = (float*)d_out + (size_t)B * AA;  // [B]

    policy_kernel<<<B / BB, 256, 0, stream>>>(
        e, q, H, r_space, r_mask, entity_emb, rel_emb,
        W1, b1, W2, b2, dist_out, ent_out);
}